// Round 1
// baseline (209.499 us; speedup 1.0000x reference)
//
#include <hip/hip_runtime.h>
#include <stdint.h>

#define IN_F   4096
#define OUT_F  4096
#define BATCH  128
#define NNZ    1600000

#define ZBLK   2048          // zero-fill blocks in k_prep
#define MT     64            // GEMM M-tile per block (4 waves x 16 rows)
#define KCH    256           // GEMM K per split-K chunk
#define NCH    16            // split-K chunks (KCH*NCH = IN_F)

typedef float f32x4_t __attribute__((ext_vector_type(4)));
typedef short s16x8_t __attribute__((ext_vector_type(8)));

// fp32 -> bf16 bits (RNE)
__device__ __forceinline__ unsigned f2bf(float f) {
  unsigned u = __float_as_uint(f);
  return (u + 0x7fffu + ((u >> 16) & 1u)) >> 16;
}

// ---------- KA: zero dense W (fp32 [OUT_F][IN_F]) + convert inp -> bf16 [BATCH][IN_F]
__global__ __launch_bounds__(256) void k_prep(const float* __restrict__ inp,
                                              float* __restrict__ Wd,
                                              unsigned* __restrict__ inpBF) {
  const int t = threadIdx.x;
  const int b = blockIdx.x;
  if (b < ZBLK) {
    // 2048 blocks * 256 thr * 8 float4 = 16,777,216 floats = OUT_F*IN_F exactly
    float4* w4 = (float4*)Wd;
    const size_t i0 = (size_t)b * 256 + t;
    const float4 z = make_float4(0.f, 0.f, 0.f, 0.f);
    #pragma unroll
    for (int j = 0; j < 8; ++j) w4[i0 + (size_t)j * (ZBLK * 256)] = z;
  } else {
    const int row = b - ZBLK;                       // 0..127
    const float4* __restrict__ src = (const float4*)(inp + (size_t)row * IN_F);
    uint4* __restrict__ dst = (uint4*)((char*)inpBF + (size_t)row * IN_F * 2);
    const float4 x0 = src[4 * t + 0];
    const float4 x1 = src[4 * t + 1];
    const float4 x2 = src[4 * t + 2];
    const float4 x3 = src[4 * t + 3];
    dst[2 * t + 0] = make_uint4(f2bf(x0.x) | (f2bf(x0.y) << 16),
                                f2bf(x0.z) | (f2bf(x0.w) << 16),
                                f2bf(x1.x) | (f2bf(x1.y) << 16),
                                f2bf(x1.z) | (f2bf(x1.w) << 16));
    dst[2 * t + 1] = make_uint4(f2bf(x2.x) | (f2bf(x2.y) << 16),
                                f2bf(x2.z) | (f2bf(x2.w) << 16),
                                f2bf(x3.x) | (f2bf(x3.y) << 16),
                                f2bf(x3.z) | (f2bf(x3.w) << 16));
  }
}

// ---------- KB: densify — scatter-add COO into dense fp32 W ----------
__global__ __launch_bounds__(256) void k_scatter(const float* __restrict__ vals,
                                                 const int* __restrict__ rows,
                                                 const int* __restrict__ cols,
                                                 float* __restrict__ Wd) {
  const int i = blockIdx.x * 256 + threadIdx.x;
  if (i >= NNZ / 4) return;
  const int4   r = ((const int4*)rows)[i];
  const int4   c = ((const int4*)cols)[i];
  const float4 v = ((const float4*)vals)[i];
  atomicAdd(&Wd[(size_t)r.x * IN_F + c.x], v.x);
  atomicAdd(&Wd[(size_t)r.y * IN_F + c.y], v.y);
  atomicAdd(&Wd[(size_t)r.z * IN_F + c.z], v.z);
  atomicAdd(&Wd[(size_t)r.w * IN_F + c.w], v.w);
}

// ---------- KC: dense GEMM  C[r][b] = sum_k W[r][k] * inpBF[b][k]  (split-K) ------
// A = W fp32 row-major (cvt to bf16 in regs); B = inpBF bf16 [BATCH][IN_F] row-major
// (i.e. the B^T convention: both operands load 8 consecutive k per lane).
// mfma_f32_16x16x32_bf16: A lane: m=lane&15, k=(lane>>4)*8+e ; B lane: n=lane&15,
// same k. C/D: m=(lane>>4)*4+j, n=lane&15 (verified m89/m91).
__global__ __launch_bounds__(256) void k_gemm(const float* __restrict__ Wd,
                                              const unsigned short* __restrict__ inpBF,
                                              float* __restrict__ part) {
  const int t    = threadIdx.x;
  const int lane = t & 63;
  const int wm   = t >> 6;                 // wave's M sub-tile, 0..3
  const int bx   = blockIdx.x;             // M tile, 0..63
  const int by   = blockIdx.y;             // K chunk, 0..NCH-1
  const int rt   = bx * MT + wm * 16;
  const int l15  = lane & 15;
  const int lk   = lane >> 4;              // k-block 0..3

  const float* __restrict__ pa =
      Wd + (size_t)(rt + l15) * IN_F + (size_t)by * KCH + lk * 8;
  const unsigned short* __restrict__ pb =
      inpBF + (size_t)l15 * IN_F + (size_t)by * KCH + lk * 8;

  f32x4_t acc[8];
  #pragma unroll
  for (int i = 0; i < 8; ++i) { acc[i][0] = 0.f; acc[i][1] = 0.f; acc[i][2] = 0.f; acc[i][3] = 0.f; }

  for (int s = 0; s < KCH / 32; ++s) {
    const float4 a0 = *(const float4*)(pa + s * 32);
    const float4 a1 = *(const float4*)(pa + s * 32 + 4);
    union { unsigned u[4]; s16x8_t v; } af;
    af.u[0] = f2bf(a0.x) | (f2bf(a0.y) << 16);
    af.u[1] = f2bf(a0.z) | (f2bf(a0.w) << 16);
    af.u[2] = f2bf(a1.x) | (f2bf(a1.y) << 16);
    af.u[3] = f2bf(a1.z) | (f2bf(a1.w) << 16);
    #pragma unroll
    for (int nf = 0; nf < 8; ++nf) {
      const s16x8_t bf = *(const s16x8_t*)(pb + (size_t)nf * 16 * IN_F + s * 32);
      acc[nf] = __builtin_amdgcn_mfma_f32_16x16x32_bf16(af.v, bf, acc[nf], 0, 0, 0);
    }
  }

  // partials layout: [NCH][BATCH][OUT_F]; lane's 4 regs are 4 consecutive r
  #pragma unroll
  for (int nf = 0; nf < 8; ++nf) {
    float* dst = part + (size_t)(by * BATCH + nf * 16 + l15) * OUT_F + rt + lk * 4;
    *(f32x4_t*)dst = acc[nf];
  }
}

// ---------- KD: reduce split-K partials + bias -> out [BATCH][OUT_F] ----------
__global__ __launch_bounds__(256) void k_reduce(const float* __restrict__ part,
                                                const float* __restrict__ bias,
                                                float* __restrict__ out) {
  const int idx = blockIdx.x * 256 + threadIdx.x;  // float4 index, 0..131071
  const int b   = idx >> 10;
  const int rq  = idx & 1023;
  float4 s = ((const float4*)bias)[rq];
  #pragma unroll
  for (int c = 0; c < NCH; ++c) {
    const float4 p = ((const float4*)part)[((size_t)(c * BATCH + b) << 10) + rq];
    s.x += p.x; s.y += p.y; s.z += p.z; s.w += p.w;
  }
  ((float4*)out)[idx] = s;
}

// ---------- fallback (tiny workspace): correct but slow ----------
__global__ __launch_bounds__(256) void k_init_out(const float* __restrict__ bias,
                                                  float* __restrict__ out) {
  const int i = blockIdx.x * 256 + threadIdx.x;
  out[i] = bias[i & (OUT_F - 1)];
}
__global__ __launch_bounds__(256) void k_atomic(const float* __restrict__ vals,
                                                const int* __restrict__ rows,
                                                const int* __restrict__ cols,
                                                const float* __restrict__ inp,
                                                float* __restrict__ out) {
  const int i = blockIdx.x * 256 + threadIdx.x;
  if (i >= NNZ) return;
  const float v = vals[i];
  const int   r = rows[i];
  const int   c = cols[i];
  for (int b = 0; b < BATCH; ++b)
    atomicAdd(&out[(size_t)b * OUT_F + r], v * inp[(size_t)b * IN_F + c]);
}

extern "C" void kernel_launch(void* const* d_in, const int* in_sizes, int n_in,
                              void* d_out, int out_size, void* d_ws, size_t ws_size,
                              hipStream_t stream) {
  const float* inp      = (const float*)d_in[0];
  const float* w_values = (const float*)d_in[1];
  const int*   w_rows   = (const int*)d_in[2];
  const int*   w_cols   = (const int*)d_in[3];
  const float* bias     = (const float*)d_in[4];
  float*       out      = (float*)d_out;

  const size_t w_bytes    = (size_t)OUT_F * IN_F * 4;          // 64 MB
  const size_t ibf_bytes  = (size_t)BATCH * IN_F * 2;          // 1 MB
  const size_t part_bytes = (size_t)NCH * BATCH * OUT_F * 4;   // 32 MB
  const size_t need = w_bytes + ibf_bytes + part_bytes + 64;

  if (ws_size >= need) {
    char* ws = (char*)d_ws;
    float*    Wd     = (float*)ws;     ws += w_bytes;
    unsigned* inpBF  = (unsigned*)ws;  ws += ibf_bytes;
    float*    part   = (float*)ws;

    k_prep<<<ZBLK + BATCH, 256, 0, stream>>>(inp, Wd, inpBF);
    k_scatter<<<(NNZ / 4 + 255) / 256, 256, 0, stream>>>(w_values, w_rows, w_cols, Wd);
    k_gemm<<<dim3(OUT_F / MT, NCH), 256, 0, stream>>>(Wd, (const unsigned short*)inpBF, part);
    k_reduce<<<(BATCH * OUT_F / 4) / 256, 256, 0, stream>>>(part, bias, out);
  } else {
    k_init_out<<<(BATCH * OUT_F) / 256, 256, 0, stream>>>(bias, out);
    k_atomic<<<(NNZ + 255) / 256, 256, 0, stream>>>(w_values, w_rows, w_cols, inp, out);
  }
}

// Round 2
// 204.590 us; speedup vs baseline: 1.0240x; 1.0240x over previous
//
#include <hip/hip_runtime.h>
#include <stdint.h>

#define IN_F   4096
#define OUT_F  4096
#define BATCH  128
#define NNZ    1600000

#define ZBLK   1024          // zero-fill blocks for bf16 W (32 MB)
#define NQUAD  (NNZ / 4)     // 400000 int4/float4 quads
#define QCHUNK 2048          // quads per chunk (8192 nnz)
#define NCHUNK 196           // ceil(400000 / 2048)
#define MT     64            // GEMM M-tile per block (4 waves x 16 rows)
#define KCH    256           // GEMM K per split-K chunk
#define NCH    16            // split-K chunks (KCH*NCH = IN_F)

typedef float f32x4_t __attribute__((ext_vector_type(4)));
typedef short s16x8_t __attribute__((ext_vector_type(8)));

// fp32 -> bf16 bits (RNE)
__device__ __forceinline__ unsigned f2bf(float f) {
  unsigned u = __float_as_uint(f);
  return (u + 0x7fffu + ((u >> 16) & 1u)) >> 16;
}

// ---------- KA: zero dense W (bf16 [OUT_F][IN_F]) + convert inp -> bf16 [BATCH][IN_F]
__global__ __launch_bounds__(256) void k_prep(const float* __restrict__ inp,
                                              unsigned* __restrict__ Wb,
                                              unsigned* __restrict__ inpBF) {
  const int t = threadIdx.x;
  const int b = blockIdx.x;
  if (b < ZBLK) {
    // 1024 blocks * 256 thr * 8 uint4 = 33,554,432 B = OUT_F*IN_F*2 exactly
    uint4* w4 = (uint4*)Wb;
    const size_t i0 = (size_t)b * 256 + t;
    const uint4 z = make_uint4(0u, 0u, 0u, 0u);
    #pragma unroll
    for (int j = 0; j < 8; ++j) w4[i0 + (size_t)j * (ZBLK * 256)] = z;
  } else {
    const int row = b - ZBLK;                       // 0..127
    const float4* __restrict__ src = (const float4*)(inp + (size_t)row * IN_F);
    uint4* __restrict__ dst = (uint4*)((char*)inpBF + (size_t)row * IN_F * 2);
    const float4 x0 = src[4 * t + 0];
    const float4 x1 = src[4 * t + 1];
    const float4 x2 = src[4 * t + 2];
    const float4 x3 = src[4 * t + 3];
    dst[2 * t + 0] = make_uint4(f2bf(x0.x) | (f2bf(x0.y) << 16),
                                f2bf(x0.z) | (f2bf(x0.w) << 16),
                                f2bf(x1.x) | (f2bf(x1.y) << 16),
                                f2bf(x1.z) | (f2bf(x1.w) << 16));
    dst[2 * t + 1] = make_uint4(f2bf(x2.x) | (f2bf(x2.y) << 16),
                                f2bf(x2.z) | (f2bf(x2.w) << 16),
                                f2bf(x3.x) | (f2bf(x3.y) << 16),
                                f2bf(x3.z) | (f2bf(x3.w) << 16));
  }
}

// ---------- KB: densify — XCD-partitioned packed-bf16 scatter-add ----------
// Block b: partition p = b&7 (rows [p*512, p*512+512)), chunk = b>>3.
// Consecutive blocks round-robin across XCDs, so each XCD's atomics stay in a
// 512-row * 8KB = 4MB slice == one XCD L2. Correctness does not depend on the
// mapping; only L2 hit rate does.
__global__ __launch_bounds__(256) void k_scatter(const float* __restrict__ vals,
                                                 const int* __restrict__ rows,
                                                 const int* __restrict__ cols,
                                                 unsigned short* __restrict__ Wb) {
  const int part  = blockIdx.x & 7;
  const int chunk = blockIdx.x >> 3;
  const int t     = threadIdx.x;

  #pragma unroll
  for (int j = 0; j < 8; ++j) {
    const int qi = chunk * QCHUNK + j * 256 + t;
    if (qi >= NQUAD) break;
    const int4   r = ((const int4*)rows)[qi];
    const int4   c = ((const int4*)cols)[qi];
    const float4 v = ((const float4*)vals)[qi];
    #pragma unroll
    for (int e = 0; e < 4; ++e) {
      const int   re = (e == 0) ? r.x : (e == 1) ? r.y : (e == 2) ? r.z : r.w;
      const int   ce = (e == 0) ? c.x : (e == 1) ? c.y : (e == 2) ? c.z : c.w;
      const float ve = (e == 0) ? v.x : (e == 1) ? v.y : (e == 2) ? v.z : v.w;
      if ((re >> 9) == part) {
        const unsigned bf = f2bf(ve);
        const unsigned data = (ce & 1) ? (bf << 16) : bf;
        unsigned short* addr = Wb + ((size_t)re * IN_F + (ce & ~1));
        asm volatile("global_atomic_pk_add_bf16 %0, %1, off"
                     :: "v"(addr), "v"(data) : "memory");
      }
    }
  }
}

// ---------- KC: dense GEMM  C[r][b] = sum_k W[r][k] * inpBF[b][k]  (split-K) ------
// A = W bf16 row-major; B = inpBF bf16 [BATCH][IN_F] row-major (B^T convention:
// both operands load 8 consecutive k per lane).
// mfma_f32_16x16x32_bf16: A lane: m=lane&15, k=(lane>>4)*8+e ; B lane: n=lane&15,
// same k. C/D: m=(lane>>4)*4+j, n=lane&15 (verified m89/m91; round-1 passed).
__global__ __launch_bounds__(256) void k_gemm(const unsigned short* __restrict__ Wb,
                                              const unsigned short* __restrict__ inpBF,
                                              float* __restrict__ part) {
  const int t    = threadIdx.x;
  const int lane = t & 63;
  const int wm   = t >> 6;                 // wave's M sub-tile, 0..3
  const int bx   = blockIdx.x;             // M tile, 0..63
  const int by   = blockIdx.y;             // K chunk, 0..NCH-1
  const int rt   = bx * MT + wm * 16;
  const int l15  = lane & 15;
  const int lk   = lane >> 4;              // k-block 0..3

  const unsigned short* __restrict__ pa =
      Wb + (size_t)(rt + l15) * IN_F + (size_t)by * KCH + lk * 8;
  const unsigned short* __restrict__ pb =
      inpBF + (size_t)l15 * IN_F + (size_t)by * KCH + lk * 8;

  f32x4_t acc[8];
  #pragma unroll
  for (int i = 0; i < 8; ++i) { acc[i][0] = 0.f; acc[i][1] = 0.f; acc[i][2] = 0.f; acc[i][3] = 0.f; }

  #pragma unroll
  for (int s = 0; s < KCH / 32; ++s) {
    const s16x8_t av = *(const s16x8_t*)(pa + s * 32);
    #pragma unroll
    for (int nf = 0; nf < 8; ++nf) {
      const s16x8_t bv = *(const s16x8_t*)(pb + (size_t)nf * 16 * IN_F + s * 32);
      acc[nf] = __builtin_amdgcn_mfma_f32_16x16x32_bf16(av, bv, acc[nf], 0, 0, 0);
    }
  }

  // partials layout: [NCH][BATCH][OUT_F]; lane's 4 regs are 4 consecutive r
  #pragma unroll
  for (int nf = 0; nf < 8; ++nf) {
    float* dst = part + (size_t)(by * BATCH + nf * 16 + l15) * OUT_F + rt + lk * 4;
    *(f32x4_t*)dst = acc[nf];
  }
}

// ---------- KD: reduce split-K partials + bias -> out [BATCH][OUT_F] ----------
__global__ __launch_bounds__(256) void k_reduce(const float* __restrict__ part,
                                                const float* __restrict__ bias,
                                                float* __restrict__ out) {
  const int idx = blockIdx.x * 256 + threadIdx.x;  // float4 index, 0..131071
  const int b   = idx >> 10;
  const int rq  = idx & 1023;
  float4 s = ((const float4*)bias)[rq];
  #pragma unroll
  for (int c = 0; c < NCH; ++c) {
    const float4 p = ((const float4*)part)[((size_t)(c * BATCH + b) << 10) + rq];
    s.x += p.x; s.y += p.y; s.z += p.z; s.w += p.w;
  }
  ((float4*)out)[idx] = s;
}

// ---------- fallback (tiny workspace): correct but slow ----------
__global__ __launch_bounds__(256) void k_init_out(const float* __restrict__ bias,
                                                  float* __restrict__ out) {
  const int i = blockIdx.x * 256 + threadIdx.x;
  out[i] = bias[i & (OUT_F - 1)];
}
__global__ __launch_bounds__(256) void k_atomic(const float* __restrict__ vals,
                                                const int* __restrict__ rows,
                                                const int* __restrict__ cols,
                                                const float* __restrict__ inp,
                                                float* __restrict__ out) {
  const int i = blockIdx.x * 256 + threadIdx.x;
  if (i >= NNZ) return;
  const float v = vals[i];
  const int   r = rows[i];
  const int   c = cols[i];
  for (int b = 0; b < BATCH; ++b)
    atomicAdd(&out[(size_t)b * OUT_F + r], v * inp[(size_t)b * IN_F + c]);
}

extern "C" void kernel_launch(void* const* d_in, const int* in_sizes, int n_in,
                              void* d_out, int out_size, void* d_ws, size_t ws_size,
                              hipStream_t stream) {
  const float* inp      = (const float*)d_in[0];
  const float* w_values = (const float*)d_in[1];
  const int*   w_rows   = (const int*)d_in[2];
  const int*   w_cols   = (const int*)d_in[3];
  const float* bias     = (const float*)d_in[4];
  float*       out      = (float*)d_out;

  const size_t w_bytes    = (size_t)OUT_F * IN_F * 2;          // 32 MB (bf16)
  const size_t ibf_bytes  = (size_t)BATCH * IN_F * 2;          // 1 MB
  const size_t part_bytes = (size_t)NCH * BATCH * OUT_F * 4;   // 32 MB
  const size_t need = w_bytes + ibf_bytes + part_bytes + 64;

  if (ws_size >= need) {
    char* ws = (char*)d_ws;
    unsigned* Wb     = (unsigned*)ws;  ws += w_bytes;
    unsigned* inpBF  = (unsigned*)ws;  ws += ibf_bytes;
    float*    part   = (float*)ws;

    k_prep<<<ZBLK + BATCH, 256, 0, stream>>>(inp, Wb, inpBF);
    k_scatter<<<NCHUNK * 8, 256, 0, stream>>>(w_values, w_rows, w_cols,
                                              (unsigned short*)Wb);
    k_gemm<<<dim3(OUT_F / MT, NCH), 256, 0, stream>>>((const unsigned short*)Wb,
                                                      (const unsigned short*)inpBF, part);
    k_reduce<<<(BATCH * OUT_F / 4) / 256, 256, 0, stream>>>(part, bias, out);
  } else {
    k_init_out<<<(BATCH * OUT_F) / 256, 256, 0, stream>>>(bias, out);
    k_atomic<<<(NNZ + 255) / 256, 256, 0, stream>>>(w_values, w_rows, w_cols, inp, out);
  }
}

// Round 3
// 124.423 us; speedup vs baseline: 1.6838x; 1.6443x over previous
//
#include <hip/hip_runtime.h>
#include <stdint.h>

#define IN_F     4096
#define OUT_F    4096
#define BATCH    128
#define NNZ      1600000
#define NSEG     250       // sort segments; block s owns entries [s*6400, +6400)
#define CHUNKSEG 6400      // NNZ / NSEG exactly
#define CNTR     4096      // cntoff stride per segment (= OUT_F)
#define DR       4         // k_dense rows per block (64 KB LDS)
#define NCH      16        // split-K chunks
#define KCH      256       // K per chunk

typedef float f32x4_t __attribute__((ext_vector_type(4)));
typedef short s16x8_t __attribute__((ext_vector_type(8)));

// fp32 -> bf16 bits (RNE)
__device__ __forceinline__ unsigned f2bf(float f) {
  unsigned u = __float_as_uint(f);
  return (u + 0x7fffu + ((u >> 16) & 1u)) >> 16;
}

// ---------- K0: convert inp -> bf16 [BATCH][IN_F] ----------
__global__ __launch_bounds__(256) void k_prep2(const float* __restrict__ inp,
                                               unsigned* __restrict__ inpBF) {
  const int t = threadIdx.x;
  const int row = blockIdx.x;                       // 0..127
  const float4* __restrict__ src = (const float4*)(inp + (size_t)row * IN_F);
  uint4* __restrict__ dst = (uint4*)((char*)inpBF + (size_t)row * IN_F * 2);
  const float4 x0 = src[4 * t + 0];
  const float4 x1 = src[4 * t + 1];
  const float4 x2 = src[4 * t + 2];
  const float4 x3 = src[4 * t + 3];
  dst[2 * t + 0] = make_uint4(f2bf(x0.x) | (f2bf(x0.y) << 16),
                              f2bf(x0.z) | (f2bf(x0.w) << 16),
                              f2bf(x1.x) | (f2bf(x1.y) << 16),
                              f2bf(x1.z) | (f2bf(x1.w) << 16));
  dst[2 * t + 1] = make_uint4(f2bf(x2.x) | (f2bf(x2.y) << 16),
                              f2bf(x2.z) | (f2bf(x2.w) << 16),
                              f2bf(x3.x) | (f2bf(x3.y) << 16),
                              f2bf(x3.z) | (f2bf(x3.w) << 16));
}

// ---------- K1: per-block LDS counting sort (round-0 verified, verbatim) ----------
__global__ __launch_bounds__(1024) void k_segscat2(const float* __restrict__ vals,
                                                   const int* __restrict__ rows,
                                                   const int* __restrict__ cols,
                                                   unsigned* __restrict__ cntoff,
                                                   unsigned* __restrict__ gentries) {
  __shared__ unsigned pos[OUT_F];
  __shared__ unsigned sebuf[CHUNKSEG];
  __shared__ unsigned wsum[16];
  const int t = threadIdx.x;
  const int s = blockIdx.x;
  const int lane = t & 63;
  const int wid  = t >> 6;

  for (int i = t; i < OUT_F; i += 1024) pos[i] = 0u;
  __syncthreads();

  const size_t vbase = (size_t)s * (CHUNKSEG / 4);
  const size_t ja = vbase + t;
  const int4   ra = ((const int4*)rows)[ja];
  const int4   ca = ((const int4*)cols)[ja];
  const float4 va = ((const float4*)vals)[ja];
  const bool hasB = (t + 1024) < (CHUNKSEG / 4);
  int4 rb = make_int4(0, 0, 0, 0), cb = rb;
  float4 vb = make_float4(0.f, 0.f, 0.f, 0.f);
  if (hasB) {
    const size_t jb = ja + 1024;
    rb = ((const int4*)rows)[jb];
    cb = ((const int4*)cols)[jb];
    vb = ((const float4*)vals)[jb];
  }

  atomicAdd(&pos[ra.x], 1u); atomicAdd(&pos[ra.y], 1u);
  atomicAdd(&pos[ra.z], 1u); atomicAdd(&pos[ra.w], 1u);
  if (hasB) {
    atomicAdd(&pos[rb.x], 1u); atomicAdd(&pos[rb.y], 1u);
    atomicAdd(&pos[rb.z], 1u); atomicAdd(&pos[rb.w], 1u);
  }
  __syncthreads();

  const unsigned c0 = pos[4 * t], c1 = pos[4 * t + 1];
  const unsigned c2 = pos[4 * t + 2], c3 = pos[4 * t + 3];
  const unsigned tsum = c0 + c1 + c2 + c3;
  unsigned incl = tsum;
  #pragma unroll
  for (int d = 1; d < 64; d <<= 1) {
    const unsigned u = __shfl_up(incl, d, 64);
    if (lane >= d) incl += u;
  }
  if (lane == 63) wsum[wid] = incl;
  __syncthreads();
  if (wid == 0) {
    const unsigned v = (lane < 16) ? wsum[lane] : 0u;
    unsigned inc2 = v;
    #pragma unroll
    for (int d = 1; d < 16; d <<= 1) {
      const unsigned u = __shfl_up(inc2, d, 64);
      if (lane >= d) inc2 += u;
    }
    if (lane < 16) wsum[lane] = inc2 - v;
  }
  __syncthreads();
  const unsigned base = wsum[wid] + (incl - tsum);
  const unsigned o0 = base, o1 = o0 + c0, o2 = o1 + c1, o3 = o2 + c2;
  ((uint4*)(cntoff + (size_t)s * CNTR))[t] =
      make_uint4((o0 << 16) | c0, (o1 << 16) | c1, (o2 << 16) | c2, (o3 << 16) | c3);
  __syncthreads();
  pos[4 * t] = o0; pos[4 * t + 1] = o1; pos[4 * t + 2] = o2; pos[4 * t + 3] = o3;
  __syncthreads();

  unsigned p;
  p = atomicAdd(&pos[ra.x], 1u); sebuf[p] = (f2bf(va.x) << 16) | (unsigned)ca.x;
  p = atomicAdd(&pos[ra.y], 1u); sebuf[p] = (f2bf(va.y) << 16) | (unsigned)ca.y;
  p = atomicAdd(&pos[ra.z], 1u); sebuf[p] = (f2bf(va.z) << 16) | (unsigned)ca.z;
  p = atomicAdd(&pos[ra.w], 1u); sebuf[p] = (f2bf(va.w) << 16) | (unsigned)ca.w;
  if (hasB) {
    p = atomicAdd(&pos[rb.x], 1u); sebuf[p] = (f2bf(vb.x) << 16) | (unsigned)cb.x;
    p = atomicAdd(&pos[rb.y], 1u); sebuf[p] = (f2bf(vb.y) << 16) | (unsigned)cb.y;
    p = atomicAdd(&pos[rb.z], 1u); sebuf[p] = (f2bf(vb.z) << 16) | (unsigned)cb.z;
    p = atomicAdd(&pos[rb.w], 1u); sebuf[p] = (f2bf(vb.w) << 16) | (unsigned)cb.w;
  }
  __syncthreads();

  uint4* __restrict__ dst = (uint4*)(gentries + (size_t)s * CHUNKSEG);
  const uint4* __restrict__ srcv = (const uint4*)sebuf;
  dst[t] = srcv[t];
  if (hasB) dst[t + 1024] = srcv[t + 1024];
}

// ---------- K2: densify from sorted segments — LDS fp32 accumulate, NO global atomics
// Block owns rows [4*bx, +4). Lane l handles (seg-sub = l>>2, row = l&3); buckets for
// a row are contiguous runs in gentries (sorted), located via cntoff.
__global__ __launch_bounds__(256) void k_dense(const unsigned* __restrict__ gentries,
                                               const unsigned* __restrict__ cntoff,
                                               unsigned* __restrict__ Wb) {
  __shared__ float lrow[DR][IN_F];                  // 64 KB
  const int t    = threadIdx.x;
  const int lane = t & 63;
  const int wid  = t >> 6;
  const int r0   = blockIdx.x * DR;

  #pragma unroll
  for (int j = 0; j < 16; ++j)
    ((float4*)lrow)[j * 256 + t] = make_float4(0.f, 0.f, 0.f, 0.f);
  __syncthreads();

  const int sl = lane >> 2;                         // 0..15
  const int rl = lane & 3;                          // 0..3
  #pragma unroll
  for (int pass = 0; pass < 4; ++pass) {
    const int s = pass * 64 + wid * 16 + sl;        // 4 waves x 16 segs x 4 passes = 256
    if (s < NSEG) {
      const unsigned co  = cntoff[(size_t)s * CNTR + r0 + rl];
      const unsigned cnt = co & 0xffffu;
      const unsigned off = co >> 16;
      const unsigned* __restrict__ src = gentries + (size_t)s * CHUNKSEG + off;
      for (unsigned i = 0; i < cnt; ++i) {
        const unsigned e = src[i];
        atomicAdd(&lrow[rl][e & 0xffffu], __uint_as_float(e & 0xffff0000u));
      }
    }
  }
  __syncthreads();

  #pragma unroll
  for (int j = 0; j < 8; ++j) {
    const int idx  = j * 256 + t;                   // uint4 index, 2048 = 4 rows * 512
    const int rowl = idx >> 9;
    const int c8   = (idx & 511) * 8;
    const float* p = &lrow[rowl][c8];
    uint4 o;
    o.x = f2bf(p[0]) | (f2bf(p[1]) << 16);
    o.y = f2bf(p[2]) | (f2bf(p[3]) << 16);
    o.z = f2bf(p[4]) | (f2bf(p[5]) << 16);
    o.w = f2bf(p[6]) | (f2bf(p[7]) << 16);
    ((uint4*)Wb)[(size_t)(r0 + rowl) * 512 + (idx & 511)] = o;
  }
}

// ---------- K3: dense GEMM with LDS-staged B ----------
// C[r][b] = sum_k W[r][k] * inpBF[b][k]. Same MFMA fragment math as verified v1;
// B now staged in LDS as [granule g=k/8][row] so ds_read_b128 addresses are
// 16B-consecutive across lanes (conflict-free, no swizzle needed).
__global__ __launch_bounds__(512) void k_gemm2(const unsigned short* __restrict__ Wb,
                                               const uint4* __restrict__ inpBF4,
                                               float* __restrict__ part) {
  __shared__ uint4 Bl[32 * 128];                    // 64 KB: [g][row]
  const int t    = threadIdx.x;
  const int lane = t & 63;
  const int wm   = t >> 6;                          // 0..7
  const int bx   = blockIdx.x;                      // M tile, 0..31
  const int by   = blockIdx.y;                      // K chunk, 0..NCH-1

  // stage B chunk [128 rows][KCH=256 k] = 4096 granules of 16B
  {
    const int r = t & 127;
    const int q = t >> 7;                           // 0..3
    #pragma unroll
    for (int j = 0; j < 8; ++j) {
      const int g = q * 8 + j;                      // 0..31
      Bl[g * 128 + r] = inpBF4[(size_t)r * 512 + by * 32 + g];
    }
  }
  __syncthreads();

  const int l15 = lane & 15;
  const int lk  = lane >> 4;                        // 0..3
  const int rt  = bx * 128 + wm * 16;
  const unsigned short* __restrict__ pa =
      Wb + (size_t)(rt + l15) * IN_F + by * KCH + lk * 8;

  f32x4_t acc[8];
  #pragma unroll
  for (int i = 0; i < 8; ++i) { acc[i][0] = 0.f; acc[i][1] = 0.f; acc[i][2] = 0.f; acc[i][3] = 0.f; }

  for (int s = 0; s < KCH / 32; ++s) {
    const s16x8_t av = *(const s16x8_t*)(pa + s * 32);
    #pragma unroll
    for (int nf = 0; nf < 8; ++nf) {
      const s16x8_t bv = *(const s16x8_t*)&Bl[(s * 4 + lk) * 128 + nf * 16 + l15];
      acc[nf] = __builtin_amdgcn_mfma_f32_16x16x32_bf16(av, bv, acc[nf], 0, 0, 0);
    }
  }

  #pragma unroll
  for (int nf = 0; nf < 8; ++nf) {
    float* dst = part + (size_t)(by * BATCH + nf * 16 + l15) * OUT_F + rt + lk * 4;
    *(f32x4_t*)dst = acc[nf];
  }
}

// ---------- K4: reduce split-K partials + bias -> out [BATCH][OUT_F] ----------
__global__ __launch_bounds__(256) void k_reduce(const float* __restrict__ part,
                                                const float* __restrict__ bias,
                                                float* __restrict__ out) {
  const int idx = blockIdx.x * 256 + threadIdx.x;   // float4 index, 0..131071
  const int b   = idx >> 10;
  const int rq  = idx & 1023;
  float4 s = ((const float4*)bias)[rq];
  #pragma unroll
  for (int c = 0; c < NCH; ++c) {
    const float4 p = ((const float4*)part)[((size_t)(c * BATCH + b) << 10) + rq];
    s.x += p.x; s.y += p.y; s.z += p.z; s.w += p.w;
  }
  ((float4*)out)[idx] = s;
}

// ---------- fallback (tiny workspace): correct but slow ----------
__global__ __launch_bounds__(256) void k_init_out(const float* __restrict__ bias,
                                                  float* __restrict__ out) {
  const int i = blockIdx.x * 256 + threadIdx.x;
  out[i] = bias[i & (OUT_F - 1)];
}
__global__ __launch_bounds__(256) void k_atomic(const float* __restrict__ vals,
                                                const int* __restrict__ rows,
                                                const int* __restrict__ cols,
                                                const float* __restrict__ inp,
                                                float* __restrict__ out) {
  const int i = blockIdx.x * 256 + threadIdx.x;
  if (i >= NNZ) return;
  const float v = vals[i];
  const int   r = rows[i];
  const int   c = cols[i];
  for (int b = 0; b < BATCH; ++b)
    atomicAdd(&out[(size_t)b * OUT_F + r], v * inp[(size_t)b * IN_F + c]);
}

extern "C" void kernel_launch(void* const* d_in, const int* in_sizes, int n_in,
                              void* d_out, int out_size, void* d_ws, size_t ws_size,
                              hipStream_t stream) {
  const float* inp      = (const float*)d_in[0];
  const float* w_values = (const float*)d_in[1];
  const int*   w_rows   = (const int*)d_in[2];
  const int*   w_cols   = (const int*)d_in[3];
  const float* bias     = (const float*)d_in[4];
  float*       out      = (float*)d_out;

  const size_t w_bytes   = (size_t)OUT_F * IN_F * 2;        // 32 MB (bf16)
  const size_t ibf_bytes = (size_t)BATCH * IN_F * 2;        // 1 MB
  const size_t part_bytes= (size_t)NCH * BATCH * OUT_F * 4; // 32 MB
  const size_t co_bytes  = (size_t)NSEG * CNTR * 4;         // 4.1 MB
  const size_t ent_bytes = (size_t)NSEG * CHUNKSEG * 4;     // 6.4 MB
  const size_t need = w_bytes + ibf_bytes + part_bytes + co_bytes + ent_bytes + 64;

  if (ws_size >= need) {
    char* ws = (char*)d_ws;
    unsigned* Wb       = (unsigned*)ws;  ws += w_bytes;
    unsigned* inpBF    = (unsigned*)ws;  ws += ibf_bytes;
    float*    part     = (float*)ws;     ws += part_bytes;
    unsigned* cntoff   = (unsigned*)ws;  ws += co_bytes;
    unsigned* gentries = (unsigned*)ws;

    k_prep2<<<BATCH, 256, 0, stream>>>(inp, inpBF);
    k_segscat2<<<NSEG, 1024, 0, stream>>>(w_values, w_rows, w_cols, cntoff, gentries);
    k_dense<<<OUT_F / DR, 256, 0, stream>>>(gentries, cntoff, (unsigned*)Wb);
    k_gemm2<<<dim3(OUT_F / 128, NCH), 512, 0, stream>>>((const unsigned short*)Wb,
                                                        (const uint4*)inpBF, part);
    k_reduce<<<(BATCH * OUT_F / 4) / 256, 256, 0, stream>>>(part, bias, out);
  } else {
    k_init_out<<<(BATCH * OUT_F) / 256, 256, 0, stream>>>(bias, out);
    k_atomic<<<(NNZ + 255) / 256, 256, 0, stream>>>(w_values, w_rows, w_cols, inp, out);
  }
}